// Round 6
// baseline (2845.936 us; speedup 1.0000x reference)
//
#include <hip/hip_runtime.h>
#include <hip/hip_fp16.h>

// FSRCNN fully fused, one 512-thr block per image, 2 px/thread. Round 6:
//  - LDS = 58752 B (< 64 KB) -> target 2 blocks/CU = 16 waves/CU.
//    Theory: >64KB/WG dynamic LDS forces 1 WG/CU (R2:153KB and R5:74.3KB both
//    pinned at ~8 waves/CU). X removed from LDS: head reads x from global
//    (L1-resident, clamped idx + branchless zero-select).
//  - Chain A/B fp16 [12][34][36] (R5 layout, absmax-neutral), tail 7x8-ch fp16
//    chunks double-buffered, R5's verified convT indexing.
//  - __launch_bounds__(512,2): proven VGPR=128, no spill.

#define TB 512
// half-index layout, phase 1 (conv chain)
#define AH 0            // fp16 [12][34][36] = 14688 halfs (bytes 0..29375)
#define BH 14688        // fp16 [12][34][36]            (bytes 29376..58751)
#define HCST 1224       // 34*36 halfs per channel
// phase 2 overlay (tail chunks, both dead regions)
#define CH0 0           // fp16 8ch x [36][38] = 10944 halfs
#define CH1 10944
#define CCH 1368        // 36*38 halfs per channel
#define LDS_BYTES 58752

__global__ void __launch_bounds__(TB, 2)
fsrcnn_fused(const float* __restrict__ x,
             const float* __restrict__ head_w, const float* __restrict__ head_b, const float* __restrict__ head_a,
             const float* __restrict__ b0_w, const float* __restrict__ b0_b, const float* __restrict__ b0_a,
             const float* __restrict__ b1_w, const float* __restrict__ b1_b,
             const float* __restrict__ b2_w, const float* __restrict__ b2_b,
             const float* __restrict__ b3_w, const float* __restrict__ b3_b,
             const float* __restrict__ b4_w, const float* __restrict__ b4_b,
             const float* __restrict__ b5_a,
             const float* __restrict__ b6_w, const float* __restrict__ b6_b, const float* __restrict__ b6_a,
             const float* __restrict__ tail_w, const float* __restrict__ tail_b,
             float* __restrict__ out)
{
    extern __shared__ float lds[];
    __half* hp = reinterpret_cast<__half*>(lds);
    const int tid = threadIdx.x;
    const int img = blockIdx.x;
    const int y  = tid >> 4;           // 0..31 interior row
    const int xi = (tid & 15) << 1;    // 0..30 interior col base, 2 px/thread

    // ---------------- zero A+B (pads must be 0) ----------------
    {
        float4* ab = reinterpret_cast<float4*>(&lds[0]);
        const float4 z4 = make_float4(0.f, 0.f, 0.f, 0.f);
        for (int i = tid; i < 3672; i += TB) ab[i] = z4;   // 14688 floats
    }
    __syncthreads();

    // ---------------- head 5x5 3->56 + prelu + b0 1x1 56->12 + prelu -> A(fp16) ----------------
    // X read directly from global: clamped indices + branchless zero-select.
    const float* xg = x + img * 3072;
    int  cidx[6];
    bool cok[6];
    #pragma unroll
    for (int t = 0; t < 6; t++) {
        const int c = xi - 2 + t;
        cok[t]  = ((unsigned)c < 32u);
        cidx[t] = (c < 0) ? 0 : ((c > 31) ? 31 : c);
    }
    float accS[12][2];
    #pragma unroll
    for (int s = 0; s < 12; s++) { const float bb = b0_b[s]; accS[s][0] = bb; accS[s][1] = bb; }
    for (int d0 = 0; d0 < 56; d0 += 14) {
        float ah[14][2];
        #pragma unroll
        for (int dd = 0; dd < 14; dd++) { const float hb = head_b[d0 + dd]; ah[dd][0] = hb; ah[dd][1] = hb; }
        #pragma unroll
        for (int ci = 0; ci < 3; ci++) {
            #pragma unroll
            for (int ky = 0; ky < 5; ky++) {
                const int r = y + ky - 2;
                const bool rok = ((unsigned)r < 32u);
                const int rr = rok ? r : 0;
                const float* rowp = xg + (ci << 10) + (rr << 5);
                float xv[6];
                #pragma unroll
                for (int t = 0; t < 6; t++) {
                    const float v = rowp[cidx[t]];
                    xv[t] = (rok && cok[t]) ? v : 0.f;
                }
                #pragma unroll
                for (int dd = 0; dd < 14; dd++) {
                    const float* wr = &head_w[((d0 + dd) * 3 + ci) * 25 + ky * 5];
                    #pragma unroll
                    for (int kx = 0; kx < 5; kx++) {
                        const float w = wr[kx];                 // uniform -> s_load
                        ah[dd][0] = fmaf(xv[kx],     w, ah[dd][0]);
                        ah[dd][1] = fmaf(xv[kx + 1], w, ah[dd][1]);
                    }
                }
            }
        }
        #pragma unroll
        for (int dd = 0; dd < 14; dd++) {
            const float al = head_a[d0 + dd];
            float v0 = ah[dd][0]; v0 = (v0 >= 0.f) ? v0 : al * v0;
            float v1 = ah[dd][1]; v1 = (v1 >= 0.f) ? v1 : al * v1;
            #pragma unroll
            for (int s = 0; s < 12; s++) {
                const float w = b0_w[s * 56 + d0 + dd];
                accS[s][0] = fmaf(w, v0, accS[s][0]);
                accS[s][1] = fmaf(w, v1, accS[s][1]);
            }
        }
    }
    #pragma unroll
    for (int s = 0; s < 12; s++) {
        const float al = b0_a[s];
        float v0 = accS[s][0]; v0 = (v0 >= 0.f) ? v0 : al * v0;
        float v1 = accS[s][1]; v1 = (v1 >= 0.f) ? v1 : al * v1;
        *reinterpret_cast<__half2*>(hp + AH + s * HCST + (y + 1) * 36 + xi + 2) =
            __floats2half2_rn(v0, v1);
    }
    __syncthreads();

    // ---------------- b1..b3: 3x3 12->12 pad1, fp16 LDS->LDS ----------------
    auto conv3 = [&](int inB, int outB, const float* __restrict__ w, const float* __restrict__ bias) {
        float acc[12][2];
        #pragma unroll
        for (int c = 0; c < 12; c++) { const float bb = bias[c]; acc[c][0] = bb; acc[c][1] = bb; }
        for (int e = 0; e < 12; e++) {
            #pragma unroll
            for (int ky = 0; ky < 3; ky++) {
                const __half2* pr = reinterpret_cast<const __half2*>(hp + inB + e * HCST + (y + ky) * 36 + xi);
                float xv[6];
                float2 f;
                f = __half22float2(pr[0]); xv[0] = f.x; xv[1] = f.y;
                f = __half22float2(pr[1]); xv[2] = f.x; xv[3] = f.y;
                f = __half22float2(pr[2]); xv[4] = f.x; xv[5] = f.y;
                #pragma unroll
                for (int c = 0; c < 12; c++) {
                    const float* wr = &w[(c * 12 + e) * 9 + ky * 3];
                    #pragma unroll
                    for (int kx = 0; kx < 3; kx++) {
                        const float wv = wr[kx];
                        acc[c][0] = fmaf(xv[1 + kx], wv, acc[c][0]);
                        acc[c][1] = fmaf(xv[2 + kx], wv, acc[c][1]);
                    }
                }
            }
        }
        #pragma unroll
        for (int c = 0; c < 12; c++)
            *reinterpret_cast<__half2*>(hp + outB + c * HCST + (y + 1) * 36 + xi + 2) =
                __floats2half2_rn(acc[c][0], acc[c][1]);
        __syncthreads();
    };
    conv3(AH, BH, b1_w, b1_b);
    conv3(BH, AH, b2_w, b2_b);
    conv3(AH, BH, b3_w, b3_b);

    // ---------------- b4: 3x3 + prelu(b5_a) -> registers g (fp32) ----------------
    float g[12][2];
    #pragma unroll
    for (int c = 0; c < 12; c++) { const float bb = b4_b[c]; g[c][0] = bb; g[c][1] = bb; }
    for (int e = 0; e < 12; e++) {
        #pragma unroll
        for (int ky = 0; ky < 3; ky++) {
            const __half2* pr = reinterpret_cast<const __half2*>(hp + BH + e * HCST + (y + ky) * 36 + xi);
            float xv[6];
            float2 f;
            f = __half22float2(pr[0]); xv[0] = f.x; xv[1] = f.y;
            f = __half22float2(pr[1]); xv[2] = f.x; xv[3] = f.y;
            f = __half22float2(pr[2]); xv[4] = f.x; xv[5] = f.y;
            #pragma unroll
            for (int c = 0; c < 12; c++) {
                const float* wr = &b4_w[(c * 12 + e) * 9 + ky * 3];
                #pragma unroll
                for (int kx = 0; kx < 3; kx++) {
                    const float wv = wr[kx];
                    g[c][0] = fmaf(xv[1 + kx], wv, g[c][0]);
                    g[c][1] = fmaf(xv[2 + kx], wv, g[c][1]);
                }
            }
        }
    }
    #pragma unroll
    for (int c = 0; c < 12; c++) {
        const float al = b5_a[c];
        float v0 = g[c][0]; g[c][0] = (v0 >= 0.f) ? v0 : al * v0;
        float v1 = g[c][1]; g[c][1] = (v1 >= 0.f) ? v1 : al * v1;
    }
    __syncthreads();   // all chain LDS reads done -> overlay chunk buffers

    // ---------------- zero both tail chunk buffers fully ----------------
    {
        float4* ch = reinterpret_cast<float4*>(&lds[0]);
        const float4 z4 = make_float4(0.f, 0.f, 0.f, 0.f);
        for (int i = tid; i < 2736; i += TB) ch[i] = z4;   // 21888 halfs
    }
    __syncthreads();

    // b6 (1x1 12->56 + prelu) for an 8-channel chunk -> fp16 LDS chunk buffer
    auto stage8 = [&](int d0, int base) {
        #pragma unroll
        for (int dd = 0; dd < 8; dd++) {
            const int d = d0 + dd;
            float v0 = b6_b[d], v1 = v0;
            #pragma unroll
            for (int s = 0; s < 12; s++) {
                const float w = b6_w[d * 12 + s];
                v0 = fmaf(w, g[s][0], v0);
                v1 = fmaf(w, g[s][1], v1);
            }
            const float al = b6_a[d];
            v0 = (v0 >= 0.f) ? v0 : al * v0;
            v1 = (v1 >= 0.f) ? v1 : al * v1;
            *reinterpret_cast<__half2*>(hp + base + dd * CCH + (y + 2) * 38 + xi + 2) =
                __floats2half2_rn(v0, v1);
        }
    };

    // ---------------- tail: 9x9 stride-2 convT 56->3, 7 chunks double-buffered ----------------
    float acc[3][2][4];   // [c][ry][q] -> out(2y+ry, 2xi+q)
    #pragma unroll
    for (int c = 0; c < 3; c++) {
        const float tb = tail_b[c];
        #pragma unroll
        for (int r = 0; r < 2; r++)
            #pragma unroll
            for (int q = 0; q < 4; q++) acc[c][r][q] = tb;
    }

    stage8(0, CH0);
    __syncthreads();

    for (int k = 0; k < 7; k++) {
        const int cur = (k & 1) ? CH1 : CH0;
        if (k < 6) stage8((k + 1) * 8, (k & 1) ? CH0 : CH1);
        const int d0 = k * 8;
        #pragma unroll
        for (int dd = 0; dd < 8; dd++) {
            const __half* hb = hp + cur + dd * CCH;
            const float* wb = &tail_w[(d0 + dd) * 243];   // [c][ky][kx], c stride 81
            #pragma unroll
            for (int j = 0; j < 5; j++) {                 // buffer row y+j; m = 4-j
                const __half2* pr = reinterpret_cast<const __half2*>(hb + (y + j) * 38 + xi);
                float xv[6];
                float2 f;
                f = __half22float2(pr[0]); xv[0] = f.x; xv[1] = f.y;
                f = __half22float2(pr[1]); xv[2] = f.x; xv[3] = f.y;
                f = __half22float2(pr[2]); xv[4] = f.x; xv[5] = f.y;
                {   // ry = 0, ky = 8-2j
                    const int kyo = (8 - 2 * j) * 9;
                    #pragma unroll
                    for (int kx = 0; kx < 9; kx++) {
                        const int n = kx >> 1, rx = kx & 1;
                        #pragma unroll
                        for (int c = 0; c < 3; c++) {
                            const float w = wb[c * 81 + kyo + kx];
                            acc[c][0][rx]     = fmaf(xv[4 - n], w, acc[c][0][rx]);
                            acc[c][0][2 + rx] = fmaf(xv[5 - n], w, acc[c][0][2 + rx]);
                        }
                    }
                }
                if (j >= 1) {   // ry = 1, ky = 9-2j
                    const int kyo = (9 - 2 * j) * 9;
                    #pragma unroll
                    for (int kx = 0; kx < 9; kx++) {
                        const int n = kx >> 1, rx = kx & 1;
                        #pragma unroll
                        for (int c = 0; c < 3; c++) {
                            const float w = wb[c * 81 + kyo + kx];
                            acc[c][1][rx]     = fmaf(xv[4 - n], w, acc[c][1][rx]);
                            acc[c][1][2 + rx] = fmaf(xv[5 - n], w, acc[c][1][2 + rx]);
                        }
                    }
                }
            }
        }
        __syncthreads();
    }

    // ---------------- store 2 rows x 4 cols per thread, per channel ----------------
    float* op = out + (img * 3) * 4096 + (2 * y) * 64 + 2 * xi;
    #pragma unroll
    for (int c = 0; c < 3; c++) {
        *reinterpret_cast<float4*>(op + c * 4096)      = make_float4(acc[c][0][0], acc[c][0][1], acc[c][0][2], acc[c][0][3]);
        *reinterpret_cast<float4*>(op + c * 4096 + 64) = make_float4(acc[c][1][0], acc[c][1][1], acc[c][1][2], acc[c][1][3]);
    }
}

extern "C" void kernel_launch(void* const* d_in, const int* in_sizes, int n_in,
                              void* d_out, int out_size, void* d_ws, size_t ws_size,
                              hipStream_t stream) {
    (void)in_sizes; (void)n_in; (void)d_ws; (void)ws_size; (void)out_size;
    const float* x      = (const float*)d_in[0];
    const float* head_w = (const float*)d_in[1];
    const float* head_b = (const float*)d_in[2];
    const float* head_a = (const float*)d_in[3];
    const float* b0_w   = (const float*)d_in[4];
    const float* b0_b   = (const float*)d_in[5];
    const float* b0_a   = (const float*)d_in[6];
    const float* b1_w   = (const float*)d_in[7];
    const float* b1_b   = (const float*)d_in[8];
    const float* b2_w   = (const float*)d_in[9];
    const float* b2_b   = (const float*)d_in[10];
    const float* b3_w   = (const float*)d_in[11];
    const float* b3_b   = (const float*)d_in[12];
    const float* b4_w   = (const float*)d_in[13];
    const float* b4_b   = (const float*)d_in[14];
    const float* b5_a   = (const float*)d_in[15];
    const float* b6_w   = (const float*)d_in[16];
    const float* b6_b   = (const float*)d_in[17];
    const float* b6_a   = (const float*)d_in[18];
    const float* tail_w = (const float*)d_in[19];
    const float* tail_b = (const float*)d_in[20];
    float* out = (float*)d_out;

    fsrcnn_fused<<<1024, TB, LDS_BYTES, stream>>>(
        x, head_w, head_b, head_a, b0_w, b0_b, b0_a,
        b1_w, b1_b, b2_w, b2_b, b3_w, b3_b, b4_w, b4_b, b5_a,
        b6_w, b6_b, b6_a, tail_w, tail_b, out);
}